// Round 1
// baseline (1792.402 us; speedup 1.0000x reference)
//
#include <hip/hip_runtime.h>
#include <stdint.h>

// B=8, S=1024, D=512, H=8, DK=512 (H*DK=4096).
// CONTRACT (decoded r0-5): inputs fp32, OUTPUT fp32, ws = 256 MiB exactly.
// R9: flash_attn pipelined — K tile double-buffered (global_load_lds, counted
// vmcnt(16), raw s_barrier: no vmcnt(0) drain in main loop), V fragments
// direct global->VGPR (B-frag layout, latency hidden under QK^T), Ps barrier
// is lgkmcnt(0)-only. setprio(1) around MFMA clusters.
typedef __attribute__((ext_vector_type(8))) short short8;
typedef __attribute__((ext_vector_type(4))) float f32x4;

__device__ __forceinline__ float bf2f(short s) {
  union { uint32_t u; float f; } x;
  x.u = ((uint32_t)(uint16_t)s) << 16;
  return x.f;
}
__device__ __forceinline__ short f2bf(float f) {
  union { float f; uint32_t u; } x;
  x.f = f;
  uint32_t r = (x.u + 0x7fffu + ((x.u >> 16) & 1u)) >> 16;
  return (short)(uint16_t)r;
}
__device__ __forceinline__ short8 cvt8(const float* p) {
  short8 r;
#pragma unroll
  for (int t = 0; t < 8; ++t) r[t] = f2bf(p[t]);
  return r;
}
// async global->LDS, 16B/lane; lds ptr must equal wave-uniform base + lane*16
__device__ __forceinline__ void g2lds16(const void* g, void* l) {
  __builtin_amdgcn_global_load_lds(
      (const __attribute__((address_space(1))) void*)g,
      (__attribute__((address_space(3))) void*)l, 16, 0, 0);
}

// ---------------------------------------------------------------------------
// K1: QKV projection (unchanged). fp32 in -> bf16 out.
// M=8192, N=4096, K=512. z=0/1 -> (B,H,S,DK); z=2 (V) -> (B,H,DK,S).
// ---------------------------------------------------------------------------
__global__ void qkv_proj(
    const float* __restrict__ qin, const float* __restrict__ kin, const float* __restrict__ vin,
    const float* __restrict__ wq, const float* __restrict__ wk, const float* __restrict__ wv,
    short* __restrict__ Qh, short* __restrict__ Kh, short* __restrict__ Vt)
{
  __shared__ __align__(16) short As[128 * 32];
  __shared__ __align__(16) short Bs[128 * 32];
  const int z = blockIdx.z;
  const float* x = (z == 0) ? qin : (z == 1) ? kin : vin;
  const float* W = (z == 0) ? wq : (z == 1) ? wk : wv;
  short* out = (z == 0) ? Qh : (z == 1) ? Kh : Vt;
  const int tid = threadIdx.x;
  const int wave = tid >> 6, lane = tid & 63;
  const int quad = lane >> 4, l15 = lane & 15;
  const int mBase = blockIdx.x * 128, nBase = blockIdx.y * 128;
  const int wm = wave >> 1, wn = wave & 1;
  const int c0 = tid, c1 = tid + 256;
  const int r0 = c0 >> 2, o0 = (c0 & 3) * 8;
  const int r1 = c1 >> 2, o1 = (c1 & 3) * 8;
  f32x4 acc[4][4] = {};

  for (int k0 = 0; k0 < 512; k0 += 32) {
    __syncthreads();
    *(short8*)(As + r0 * 32 + o0) = cvt8(x + (long)(mBase + r0) * 512 + k0 + o0);
    *(short8*)(As + r1 * 32 + o1) = cvt8(x + (long)(mBase + r1) * 512 + k0 + o1);
    *(short8*)(Bs + r0 * 32 + o0) = cvt8(W + (long)(nBase + r0) * 512 + k0 + o0);
    *(short8*)(Bs + r1 * 32 + o1) = cvt8(W + (long)(nBase + r1) * 512 + k0 + o1);
    __syncthreads();
    short8 a[4], b[4];
#pragma unroll
    for (int mi = 0; mi < 4; ++mi)
      a[mi] = *(const short8*)(As + (wm * 64 + mi * 16 + l15) * 32 + quad * 8);
#pragma unroll
    for (int ni = 0; ni < 4; ++ni)
      b[ni] = *(const short8*)(Bs + (wn * 64 + ni * 16 + l15) * 32 + quad * 8);
#pragma unroll
    for (int mi = 0; mi < 4; ++mi)
#pragma unroll
      for (int ni = 0; ni < 4; ++ni)
        acc[mi][ni] = __builtin_amdgcn_mfma_f32_16x16x32_bf16(a[mi], b[ni], acc[mi][ni], 0, 0, 0);
  }
#pragma unroll
  for (int mi = 0; mi < 4; ++mi) {
#pragma unroll
    for (int ni = 0; ni < 4; ++ni) {
      int n = nBase + wn * 64 + ni * 16 + l15;
      int h = n >> 9, d = n & 511;
#pragma unroll
      for (int r = 0; r < 4; ++r) {
        int m = mBase + wm * 64 + mi * 16 + quad * 4 + r;
        int b = m >> 10, s = m & 1023;
        long idx;
        if (z == 2) idx = ((long)(b * 8 + h) * 512 + d) * 1024 + s;   // V: (B,H,DK,S)
        else        idx = ((long)(b * 8 + h) * 1024 + s) * 512 + d;   // (B,H,S,DK)
        out[idx] = f2bf(acc[mi][ni][r]);
      }
    }
  }
}

// ---------------------------------------------------------------------------
// K2: flash attention v4 (pipelined).
//  - Ks double-buffered, XOR-swizzled (chunk j of key-row r at r*64+(j^(r&7)))
//    staged via global_load_lds one tile AHEAD; main-loop waits are counted
//    (vmcnt(16)) + raw s_barrier — no full vmem drain per iteration.
//  - V fragments loaded straight to VGPRs (wave's own 128-d slice, 8x short8,
//    B-frag layout, 64B-line efficient, L2-resident) at the top of the
//    iteration; compiler's own counted vmcnt hides them under QK^T+softmax.
//  - Ps rows padded to 40 shorts (conflict-free); Ps barrier = lgkmcnt(0) only.
//  - PV d-split across waves; denominators broadcast via lred[64].
//  - XCD swizzle: lin = (bh&7) + 8*(qt + 16*(bh>>3)).
// ---------------------------------------------------------------------------
__global__ __launch_bounds__(256, 2) void flash_attn(
    const short* __restrict__ Qh, const short* __restrict__ Kh,
    const short* __restrict__ Vt, short* __restrict__ ctx)
{
  __shared__ __align__(16) short Ks[2][32 * 512];  // 64 KB, swizzled, dbuf
  __shared__ __align__(16) short Ps[4 * 16 * 40];  // 5 KB, padded rows
  __shared__ float lred[64];
  const int tid = threadIdx.x;
  const int wave = tid >> 6, lane = tid & 63;
  const int quad = lane >> 4, l15 = lane & 15;
  const int lin = blockIdx.x;
  const int qt = (lin >> 3) & 15;
  const int bh = ((lin >> 7) << 3) | (lin & 7);
  const float C = 0.0637587234f;  // log2(e)/sqrt(512)

  // Q fragments for this wave's q-group (A-operand: A[m=l15][k=quad*8+j])
  const short* qbase = Qh + ((long)bh * 1024 + qt * 64 + wave * 16 + l15) * 512 + quad * 8;
  short8 qf[16];
#pragma unroll
  for (int c = 0; c < 16; ++c) qf[c] = *(const short8*)(qbase + c * 32);

  const short* kbase = Kh + (long)bh * 1024 * 512;
  // V B-frag base: row d = wave*128 + t*16 + l15, col chunk quad*8 (+kt*32)
  const short* vbase = Vt + ((long)bh * 512 + wave * 128 + l15) * 1024 + quad * 8;

  f32x4 acc[4][8] = {};               // O: [q-group][d-tile of this wave's slice]
  float l[4] = {0.f, 0.f, 0.f, 0.f};  // partial denominators, own q-group

  // prologue: stage K tile 0 into Ks[0]
#pragma unroll
  for (int i = 0; i < 8; ++i) {
    int c = i * 256 + tid;
    int r = c >> 6, j = (c & 63) ^ (r & 7);
    g2lds16(kbase + (long)r * 512 + j * 8, (char*)Ks + c * 16);
  }

  for (int kt = 0; kt < 32; ++kt) {
    // (a) V fragments for THIS tile -> regs (latency hides under QK^T+softmax)
    short8 vf[8];
#pragma unroll
    for (int t = 0; t < 8; ++t)
      vf[t] = *(const short8*)(vbase + t * 16384 + kt * 32);
    // (b) stage NEXT K tile into the other buffer (kt=31 wraps: harmless refill)
    {
      const int ktn = (kt + 1) & 31;
      const int buf = (kt + 1) & 1;
#pragma unroll
      for (int i = 0; i < 8; ++i) {
        int c = i * 256 + tid;
        int r = c >> 6, j = (c & 63) ^ (r & 7);
        g2lds16(kbase + (long)(ktn * 32 + r) * 512 + j * 8,
                (char*)Ks + buf * 32768 + c * 16);
      }
    }
    // B1: own K(kt) staging done (vf(kt)+K(kt+1)=16 newer ops stay in flight);
    // barrier => ALL waves' K(kt) rows landed. sched_barrier pins ds_reads below.
    asm volatile("s_waitcnt vmcnt(16)" ::: "memory");
    __builtin_amdgcn_s_barrier();
    __builtin_amdgcn_sched_barrier(0);

    // S = Q K^T : own q-group x 32 keys, from Ks[kt&1]
    const short* kcur = Ks[kt & 1];
    f32x4 sacc[2] = {};
    __builtin_amdgcn_s_setprio(1);
#pragma unroll
    for (int nt = 0; nt < 2; ++nt)
#pragma unroll
      for (int c = 0; c < 16; ++c) {
        int row = nt * 16 + l15;
        int j = (c * 4 + quad) ^ (row & 7);
        short8 kf = *(const short8*)(kcur + row * 512 + j * 8);
        sacc[nt] = __builtin_amdgcn_mfma_f32_16x16x32_bf16(qf[c], kf, sacc[nt], 0, 0, 0);
      }
    __builtin_amdgcn_s_setprio(0);
    // p = exp2(s*C); partial row-sums; P into padded LDS (C-layout -> A-layout)
#pragma unroll
    for (int r = 0; r < 4; ++r) {
      float p0 = exp2f(sacc[0][r] * C);
      float p1 = exp2f(sacc[1][r] * C);
      Ps[wave * 640 + (quad * 4 + r) * 40 + l15]      = f2bf(p0);
      Ps[wave * 640 + (quad * 4 + r) * 40 + 16 + l15] = f2bf(p1);
      float t = p0 + p1;
      t += __shfl_xor(t, 1);
      t += __shfl_xor(t, 2);
      t += __shfl_xor(t, 4);
      t += __shfl_xor(t, 8);
      l[r] += t;
    }
    // B2: own Ps writes landed (lgkm only — NO vmem drain; K(kt+1) stays in
    // flight; vf waited by the compiler's counted vmcnt at first use below).
    asm volatile("s_waitcnt lgkmcnt(0)" ::: "memory");
    __builtin_amdgcn_s_barrier();
    __builtin_amdgcn_sched_barrier(0);

    // O += P V : all 4 q-groups x this wave's 128-d slice (vf hoisted, reused)
    __builtin_amdgcn_s_setprio(1);
#pragma unroll
    for (int g = 0; g < 4; ++g) {
      short8 pf = *(const short8*)(Ps + g * 640 + l15 * 40 + quad * 8);
#pragma unroll
      for (int t = 0; t < 8; ++t)
        acc[g][t] = __builtin_amdgcn_mfma_f32_16x16x32_bf16(pf, vf[t], acc[g][t], 0, 0, 0);
    }
    __builtin_amdgcn_s_setprio(0);
  }
  // broadcast denominators
  if (l15 == 0) {
#pragma unroll
    for (int r = 0; r < 4; ++r) lred[wave * 16 + quad * 4 + r] = l[r];
  }
  __syncthreads();  // full drain here is fine (also retires the wrapped K stage)
  // epilogue: /l, store ctx (B,S,H*DK), this wave's d-slice
  const int b = bh >> 3, h = bh & 7;
#pragma unroll
  for (int g = 0; g < 4; ++g) {
#pragma unroll
    for (int r = 0; r < 4; ++r) {
      float inv = 1.0f / lred[g * 16 + quad * 4 + r];
      int qrow = qt * 64 + g * 16 + quad * 4 + r;
      long base = ((long)(b * 1024 + qrow)) * 4096 + h * 512 + wave * 128;
#pragma unroll
      for (int t = 0; t < 8; ++t)
        ctx[base + t * 16 + l15] = f2bf(acc[g][t][r] * inv);
    }
  }
}

// ---------------------------------------------------------------------------
// K3: fc + residual (unchanged). M=8192, N=512, K=4096.
// ---------------------------------------------------------------------------
__global__ void fc_gemm(
    const short* __restrict__ A, const float* __restrict__ W,
    const float* __restrict__ resid, float* __restrict__ Y)
{
  __shared__ __align__(16) short As[128 * 32];
  __shared__ __align__(16) short Bs[128 * 32];
  const int tid = threadIdx.x;
  const int wave = tid >> 6, lane = tid & 63;
  const int quad = lane >> 4, l15 = lane & 15;
  const int mBase = blockIdx.x * 128, nBase = blockIdx.y * 128;
  const int wm = wave >> 1, wn = wave & 1;
  const int c0 = tid, c1 = tid + 256;
  const int r0 = c0 >> 2, o0 = (c0 & 3) * 8;
  const int r1 = c1 >> 2, o1 = (c1 & 3) * 8;
  f32x4 acc[4][4] = {};

  for (int k0 = 0; k0 < 4096; k0 += 32) {
    __syncthreads();
    *(short8*)(As + r0 * 32 + o0) = *(const short8*)(A + (long)(mBase + r0) * 4096 + k0 + o0);
    *(short8*)(As + r1 * 32 + o1) = *(const short8*)(A + (long)(mBase + r1) * 4096 + k0 + o1);
    *(short8*)(Bs + r0 * 32 + o0) = cvt8(W + (long)(nBase + r0) * 4096 + k0 + o0);
    *(short8*)(Bs + r1 * 32 + o1) = cvt8(W + (long)(nBase + r1) * 4096 + k0 + o1);
    __syncthreads();
    short8 a[4], b[4];
#pragma unroll
    for (int mi = 0; mi < 4; ++mi)
      a[mi] = *(const short8*)(As + (wm * 64 + mi * 16 + l15) * 32 + quad * 8);
#pragma unroll
    for (int ni = 0; ni < 4; ++ni)
      b[ni] = *(const short8*)(Bs + (wn * 64 + ni * 16 + l15) * 32 + quad * 8);
#pragma unroll
    for (int mi = 0; mi < 4; ++mi)
#pragma unroll
      for (int ni = 0; ni < 4; ++ni)
        acc[mi][ni] = __builtin_amdgcn_mfma_f32_16x16x32_bf16(a[mi], b[ni], acc[mi][ni], 0, 0, 0);
  }
#pragma unroll
  for (int mi = 0; mi < 4; ++mi)
#pragma unroll
    for (int ni = 0; ni < 4; ++ni) {
      int n = nBase + wn * 64 + ni * 16 + l15;
#pragma unroll
      for (int r = 0; r < 4; ++r) {
        int m = mBase + wm * 64 + mi * 16 + quad * 4 + r;
        long idx = (long)m * 512 + n;
        Y[idx] = acc[mi][ni][r] + resid[idx];
      }
    }
}

// ---------------------------------------------------------------------------
// K4: LayerNorm (unchanged).
// ---------------------------------------------------------------------------
__global__ void layernorm(
    const float* __restrict__ Y, const float* __restrict__ gamma,
    const float* __restrict__ beta, float* __restrict__ out)
{
  const int tid = threadIdx.x;
  const int wave = tid >> 6, lane = tid & 63;
  const long row = (long)blockIdx.x * 4 + wave;
  f32x4 xa = *(const f32x4*)(Y + row * 512 + lane * 8);
  f32x4 xb = *(const f32x4*)(Y + row * 512 + lane * 8 + 4);
  float x[8];
  float s = 0.f, s2 = 0.f;
#pragma unroll
  for (int i = 0; i < 4; ++i) { x[i] = xa[i]; x[i + 4] = xb[i]; }
#pragma unroll
  for (int i = 0; i < 8; ++i) { s += x[i]; s2 += x[i] * x[i]; }
#pragma unroll
  for (int m = 1; m < 64; m <<= 1) { s += __shfl_xor(s, m); s2 += __shfl_xor(s2, m); }
  float mu = s * (1.0f / 512.0f);
  float var = s2 * (1.0f / 512.0f) - mu * mu;
  float rs = rsqrtf(var + 1e-6f);
  f32x4 oa, ob;
#pragma unroll
  for (int i = 0; i < 4; ++i) {
    oa[i] = (x[i] - mu) * rs * gamma[lane * 8 + i] + beta[lane * 8 + i];
    ob[i] = (x[i + 4] - mu) * rs * gamma[lane * 8 + 4 + i] + beta[lane * 8 + 4 + i];
  }
  *(f32x4*)(out + row * 512 + lane * 8) = oa;
  *(f32x4*)(out + row * 512 + lane * 8 + 4) = ob;
}

extern "C" void kernel_launch(void* const* d_in, const int* in_sizes, int n_in,
                              void* d_out, int out_size, void* d_ws, size_t ws_size,
                              hipStream_t stream) {
  const float* q     = (const float*)d_in[0];
  const float* k     = (const float*)d_in[1];
  const float* v     = (const float*)d_in[2];
  const float* wq    = (const float*)d_in[3];
  const float* wk    = (const float*)d_in[4];
  const float* wv    = (const float*)d_in[5];
  const float* wfc   = (const float*)d_in[6];
  const float* gamma = (const float*)d_in[7];
  const float* beta  = (const float*)d_in[8];
  float* out = (float*)d_out;
  char* ws = (char*)d_ws;
  short* Qh  = (short*)(ws);
  short* Kh  = (short*)(ws + 67108864);
  short* Vt  = (short*)(ws + 134217728);
  short* ctx = (short*)(ws + 201326592);
  float* Y   = (float*)(ws);  // fp32, aliases dead Qh (stream order)

  qkv_proj<<<dim3(64, 32, 3), 256, 0, stream>>>(q, k, v, wq, wk, wv, Qh, Kh, Vt);
  flash_attn<<<dim3(1024), 256, 0, stream>>>(Qh, Kh, Vt, ctx);
  fc_gemm<<<dim3(64, 4), 256, 0, stream>>>(ctx, wfc, q, Y);
  layernorm<<<2048, 256, 0, stream>>>(Y, gamma, beta, out);
}

// Round 2
// 878.553 us; speedup vs baseline: 2.0402x; 2.0402x over previous
//
#include <hip/hip_runtime.h>
#include <hip/hip_bf16.h>
#include <stdint.h>

// B=8, S=1024, D=512, H=8, DK=512 (H*DK=4096).
// CONTRACT (decoded r0-5): inputs fp32, OUTPUT fp32, ws = 256 MiB exactly.
// R10: flash_attn reverted to R8 lockstep structure (R9's free-running pipeline
// destroyed cross-block L2 reuse: FETCH 308MB->2.06GB). One bounded change:
// B1 = vmcnt(8)+s_barrier so V's DMA hides under QK^T+softmax; pre-PV
// __syncthreads() still drains vmcnt(0) -> lockstep/L2-sharing preserved.
// qkv/fc: f2bf -> __float2bfloat16 (hw cvt, ~5x less staging VALU);
// fc A-stage -> global_load_lds (A already bf16).
typedef __attribute__((ext_vector_type(8))) short short8;
typedef __attribute__((ext_vector_type(4))) float f32x4;

__device__ __forceinline__ float bf2f(short s) {
  union { uint32_t u; float f; } x;
  x.u = ((uint32_t)(uint16_t)s) << 16;
  return x.f;
}
__device__ __forceinline__ short f2bf(float f) {
  __hip_bfloat16 h = __float2bfloat16(f);  // v_cvt-class RNE, not 5 int ops
  union { __hip_bfloat16 h; short s; } x;
  x.h = h;
  return x.s;
}
__device__ __forceinline__ short8 cvt8(const float* p) {
  short8 r;
#pragma unroll
  for (int t = 0; t < 8; ++t) r[t] = f2bf(p[t]);
  return r;
}
// async global->LDS, 16B/lane; lds ptr must equal wave-uniform base + lane*16
__device__ __forceinline__ void g2lds16(const void* g, void* l) {
  __builtin_amdgcn_global_load_lds(
      (const __attribute__((address_space(1))) void*)g,
      (__attribute__((address_space(3))) void*)l, 16, 0, 0);
}

// ---------------------------------------------------------------------------
// K1: QKV projection. fp32 in -> bf16 out.
// M=8192, N=4096, K=512. z=0/1 -> (B,H,S,DK); z=2 (V) -> (B,H,DK,S).
// Only change vs R8: fast f2bf (staging was VALU-bound on manual rounding).
// ---------------------------------------------------------------------------
__global__ void qkv_proj(
    const float* __restrict__ qin, const float* __restrict__ kin, const float* __restrict__ vin,
    const float* __restrict__ wq, const float* __restrict__ wk, const float* __restrict__ wv,
    short* __restrict__ Qh, short* __restrict__ Kh, short* __restrict__ Vt)
{
  __shared__ __align__(16) short As[128 * 32];
  __shared__ __align__(16) short Bs[128 * 32];
  const int z = blockIdx.z;
  const float* x = (z == 0) ? qin : (z == 1) ? kin : vin;
  const float* W = (z == 0) ? wq : (z == 1) ? wk : wv;
  short* out = (z == 0) ? Qh : (z == 1) ? Kh : Vt;
  const int tid = threadIdx.x;
  const int wave = tid >> 6, lane = tid & 63;
  const int quad = lane >> 4, l15 = lane & 15;
  const int mBase = blockIdx.x * 128, nBase = blockIdx.y * 128;
  const int wm = wave >> 1, wn = wave & 1;
  const int c0 = tid, c1 = tid + 256;
  const int r0 = c0 >> 2, o0 = (c0 & 3) * 8;
  const int r1 = c1 >> 2, o1 = (c1 & 3) * 8;
  f32x4 acc[4][4] = {};

  for (int k0 = 0; k0 < 512; k0 += 32) {
    __syncthreads();
    *(short8*)(As + r0 * 32 + o0) = cvt8(x + (long)(mBase + r0) * 512 + k0 + o0);
    *(short8*)(As + r1 * 32 + o1) = cvt8(x + (long)(mBase + r1) * 512 + k0 + o1);
    *(short8*)(Bs + r0 * 32 + o0) = cvt8(W + (long)(nBase + r0) * 512 + k0 + o0);
    *(short8*)(Bs + r1 * 32 + o1) = cvt8(W + (long)(nBase + r1) * 512 + k0 + o1);
    __syncthreads();
    short8 a[4], b[4];
#pragma unroll
    for (int mi = 0; mi < 4; ++mi)
      a[mi] = *(const short8*)(As + (wm * 64 + mi * 16 + l15) * 32 + quad * 8);
#pragma unroll
    for (int ni = 0; ni < 4; ++ni)
      b[ni] = *(const short8*)(Bs + (wn * 64 + ni * 16 + l15) * 32 + quad * 8);
#pragma unroll
    for (int mi = 0; mi < 4; ++mi)
#pragma unroll
      for (int ni = 0; ni < 4; ++ni)
        acc[mi][ni] = __builtin_amdgcn_mfma_f32_16x16x32_bf16(a[mi], b[ni], acc[mi][ni], 0, 0, 0);
  }
#pragma unroll
  for (int mi = 0; mi < 4; ++mi) {
#pragma unroll
    for (int ni = 0; ni < 4; ++ni) {
      int n = nBase + wn * 64 + ni * 16 + l15;
      int h = n >> 9, d = n & 511;
#pragma unroll
      for (int r = 0; r < 4; ++r) {
        int m = mBase + wm * 64 + mi * 16 + quad * 4 + r;
        int b = m >> 10, s = m & 1023;
        long idx;
        if (z == 2) idx = ((long)(b * 8 + h) * 512 + d) * 1024 + s;   // V: (B,H,DK,S)
        else        idx = ((long)(b * 8 + h) * 1024 + s) * 512 + d;   // (B,H,S,DK)
        out[idx] = f2bf(acc[mi][ni][r]);
      }
    }
  }
}

// ---------------------------------------------------------------------------
// K2: flash attention (R8 lockstep structure).
//  - Ks XOR-swizzled: chunk j of key-row r lives at r*64 + (j ^ (r&7)).
//  - Vs XOR-swizzled: chunk j of d-row lives at d*4 + (j ^ (d&3)).
//  - Ps rows padded to 40 shorts.
//  - B1 split: vmcnt(8) waits K only; V's 8 DMAs stay in flight under
//    QK^T+softmax; B2 (__syncthreads) drains vmcnt(0) -> lockstep preserved,
//    cross-block L2 sharing of K/V tiles intact (R9 lesson).
//  - PV d-split across waves; denominators broadcast via lred[64].
//  - XCD swizzle: lin = (bh&7) + 8*(qt + 16*(bh>>3)).
// ---------------------------------------------------------------------------
__global__ __launch_bounds__(256, 2) void flash_attn(
    const short* __restrict__ Qh, const short* __restrict__ Kh,
    const short* __restrict__ Vt, short* __restrict__ ctx)
{
  __shared__ __align__(16) short Ks[32 * 512];    // 32 KB, swizzled
  __shared__ __align__(16) short Vs[512 * 32];    // 32 KB, swizzled
  __shared__ __align__(16) short Ps[4 * 16 * 40]; // 5 KB, padded rows
  __shared__ float lred[64];
  const int tid = threadIdx.x;
  const int wave = tid >> 6, lane = tid & 63;
  const int quad = lane >> 4, l15 = lane & 15;
  const int lin = blockIdx.x;
  const int qt = (lin >> 3) & 15;
  const int bh = ((lin >> 7) << 3) | (lin & 7);
  const float C = 0.0637587234f;  // log2(e)/sqrt(512)

  // Q fragments for this wave's q-group (A-operand: A[m=l15][k=quad*8+j])
  const short* qbase = Qh + ((long)bh * 1024 + qt * 64 + wave * 16 + l15) * 512 + quad * 8;
  short8 qf[16];
#pragma unroll
  for (int c = 0; c < 16; ++c) qf[c] = *(const short8*)(qbase + c * 32);

  f32x4 acc[4][8] = {};               // O: [q-group][d-tile of this wave's slice]
  float l[4] = {0.f, 0.f, 0.f, 0.f};  // partial denominators, own q-group

  for (int kt = 0; kt < 32; ++kt) {
    __syncthreads();  // B0: prior iter's Ks/Vs/Ps reads complete before overwrite
#pragma unroll
    for (int i = 0; i < 8; ++i) {     // K tile: source chunk permuted per row
      int c = i * 256 + tid;
      int r = c >> 6, j = (c & 63) ^ (r & 7);
      g2lds16(Kh + ((long)bh * 1024 + kt * 32 + r) * 512 + j * 8, (char*)Ks + c * 16);
    }
    __builtin_amdgcn_sched_barrier(0);  // pin issue order: K DMAs before V DMAs
#pragma unroll
    for (int i = 0; i < 8; ++i) {     // V tile: source chunk permuted per row
      int c = i * 256 + tid;
      int d = c >> 2, j = (c & 3) ^ (d & 3);
      g2lds16(Vt + ((long)bh * 512 + d) * 1024 + kt * 32 + j * 8, (char*)Vs + c * 16);
    }
    __builtin_amdgcn_sched_barrier(0);
    // B1: wait K's 8 DMAs only (V's 8 remain in flight, hidden under QK^T)
    asm volatile("s_waitcnt vmcnt(8)" ::: "memory");
    __builtin_amdgcn_s_barrier();
    __builtin_amdgcn_sched_barrier(0);

    // S = Q K^T : own q-group x 32 keys
    f32x4 sacc[2] = {};
#pragma unroll
    for (int nt = 0; nt < 2; ++nt)
#pragma unroll
      for (int c = 0; c < 16; ++c) {
        int row = nt * 16 + l15;
        int j = (c * 4 + quad) ^ (row & 7);
        short8 kf = *(const short8*)(Ks + row * 512 + j * 8);
        sacc[nt] = __builtin_amdgcn_mfma_f32_16x16x32_bf16(qf[c], kf, sacc[nt], 0, 0, 0);
      }
    // p = exp2(s*C); partial row-sums; P into padded LDS (C-layout -> A-layout)
#pragma unroll
    for (int r = 0; r < 4; ++r) {
      float p0 = exp2f(sacc[0][r] * C);
      float p1 = exp2f(sacc[1][r] * C);
      Ps[wave * 640 + (quad * 4 + r) * 40 + l15]      = f2bf(p0);
      Ps[wave * 640 + (quad * 4 + r) * 40 + 16 + l15] = f2bf(p1);
      float t = p0 + p1;
      t += __shfl_xor(t, 1);
      t += __shfl_xor(t, 2);
      t += __shfl_xor(t, 4);
      t += __shfl_xor(t, 8);
      l[r] += t;
    }
    __syncthreads();  // B2: full drain (vmcnt->0: Vs landed; lgkm: Ps visible)

    // O += P V : all 4 q-groups x this wave's 128-d slice
#pragma unroll
    for (int g = 0; g < 4; ++g) {
      short8 pf = *(const short8*)(Ps + g * 640 + l15 * 40 + quad * 8);
#pragma unroll
      for (int t = 0; t < 8; ++t) {
        int row = wave * 128 + t * 16 + l15;
        int j = quad ^ (row & 3);
        short8 vf = *(const short8*)(Vs + row * 32 + j * 8);
        acc[g][t] = __builtin_amdgcn_mfma_f32_16x16x32_bf16(pf, vf, acc[g][t], 0, 0, 0);
      }
    }
  }
  // broadcast denominators
  if (l15 == 0) {
#pragma unroll
    for (int r = 0; r < 4; ++r) lred[wave * 16 + quad * 4 + r] = l[r];
  }
  __syncthreads();
  // epilogue: /l, store ctx (B,S,H*DK), this wave's d-slice
  const int b = bh >> 3, h = bh & 7;
#pragma unroll
  for (int g = 0; g < 4; ++g) {
#pragma unroll
    for (int r = 0; r < 4; ++r) {
      float inv = 1.0f / lred[g * 16 + quad * 4 + r];
      int qrow = qt * 64 + g * 16 + quad * 4 + r;
      long base = ((long)(b * 1024 + qrow)) * 4096 + h * 512 + wave * 128;
#pragma unroll
      for (int t = 0; t < 8; ++t)
        ctx[base + t * 16 + l15] = f2bf(acc[g][t][r] * inv);
    }
  }
}

// ---------------------------------------------------------------------------
// K3: fc + residual. M=8192, N=512, K=4096.
// Changes vs R8: A-stage via global_load_lds (A already bf16, LDS layout is
// lane-linear: dest byte = c*16); B-stage uses fast f2bf.
// ---------------------------------------------------------------------------
__global__ void fc_gemm(
    const short* __restrict__ A, const float* __restrict__ W,
    const float* __restrict__ resid, float* __restrict__ Y)
{
  __shared__ __align__(16) short As[128 * 32];
  __shared__ __align__(16) short Bs[128 * 32];
  const int tid = threadIdx.x;
  const int wave = tid >> 6, lane = tid & 63;
  const int quad = lane >> 4, l15 = lane & 15;
  const int mBase = blockIdx.x * 128, nBase = blockIdx.y * 128;
  const int wm = wave >> 1, wn = wave & 1;
  const int c0 = tid, c1 = tid + 256;
  const int r0 = c0 >> 2, o0 = (c0 & 3) * 8;
  const int r1 = c1 >> 2, o1 = (c1 & 3) * 8;
  f32x4 acc[4][4] = {};

  for (int k0 = 0; k0 < 4096; k0 += 32) {
    __syncthreads();
    g2lds16(A + (long)(mBase + r0) * 4096 + k0 + o0, (char*)As + c0 * 16);
    g2lds16(A + (long)(mBase + r1) * 4096 + k0 + o1, (char*)As + c1 * 16);
    *(short8*)(Bs + r0 * 32 + o0) = cvt8(W + (long)(nBase + r0) * 4096 + k0 + o0);
    *(short8*)(Bs + r1 * 32 + o1) = cvt8(W + (long)(nBase + r1) * 4096 + k0 + o1);
    __syncthreads();  // drains vmcnt (A DMA) + lgkm (B stores)
    short8 a[4], b[4];
#pragma unroll
    for (int mi = 0; mi < 4; ++mi)
      a[mi] = *(const short8*)(As + (wm * 64 + mi * 16 + l15) * 32 + quad * 8);
#pragma unroll
    for (int ni = 0; ni < 4; ++ni)
      b[ni] = *(const short8*)(Bs + (wn * 64 + ni * 16 + l15) * 32 + quad * 8);
#pragma unroll
    for (int mi = 0; mi < 4; ++mi)
#pragma unroll
      for (int ni = 0; ni < 4; ++ni)
        acc[mi][ni] = __builtin_amdgcn_mfma_f32_16x16x32_bf16(a[mi], b[ni], acc[mi][ni], 0, 0, 0);
  }
#pragma unroll
  for (int mi = 0; mi < 4; ++mi)
#pragma unroll
    for (int ni = 0; ni < 4; ++ni) {
      int n = nBase + wn * 64 + ni * 16 + l15;
#pragma unroll
      for (int r = 0; r < 4; ++r) {
        int m = mBase + wm * 64 + mi * 16 + quad * 4 + r;
        long idx = (long)m * 512 + n;
        Y[idx] = acc[mi][ni][r] + resid[idx];
      }
    }
}

// ---------------------------------------------------------------------------
// K4: LayerNorm (unchanged).
// ---------------------------------------------------------------------------
__global__ void layernorm(
    const float* __restrict__ Y, const float* __restrict__ gamma,
    const float* __restrict__ beta, float* __restrict__ out)
{
  const int tid = threadIdx.x;
  const int wave = tid >> 6, lane = tid & 63;
  const long row = (long)blockIdx.x * 4 + wave;
  f32x4 xa = *(const f32x4*)(Y + row * 512 + lane * 8);
  f32x4 xb = *(const f32x4*)(Y + row * 512 + lane * 8 + 4);
  float x[8];
  float s = 0.f, s2 = 0.f;
#pragma unroll
  for (int i = 0; i < 4; ++i) { x[i] = xa[i]; x[i + 4] = xb[i]; }
#pragma unroll
  for (int i = 0; i < 8; ++i) { s += x[i]; s2 += x[i] * x[i]; }
#pragma unroll
  for (int m = 1; m < 64; m <<= 1) { s += __shfl_xor(s, m); s2 += __shfl_xor(s2, m); }
  float mu = s * (1.0f / 512.0f);
  float var = s2 * (1.0f / 512.0f) - mu * mu;
  float rs = rsqrtf(var + 1e-6f);
  f32x4 oa, ob;
#pragma unroll
  for (int i = 0; i < 4; ++i) {
    oa[i] = (x[i] - mu) * rs * gamma[lane * 8 + i] + beta[lane * 8 + i];
    ob[i] = (x[i + 4] - mu) * rs * gamma[lane * 8 + 4 + i] + beta[lane * 8 + 4 + i];
  }
  *(f32x4*)(out + row * 512 + lane * 8) = oa;
  *(f32x4*)(out + row * 512 + lane * 8 + 4) = ob;
}

extern "C" void kernel_launch(void* const* d_in, const int* in_sizes, int n_in,
                              void* d_out, int out_size, void* d_ws, size_t ws_size,
                              hipStream_t stream) {
  const float* q     = (const float*)d_in[0];
  const float* k     = (const float*)d_in[1];
  const float* v     = (const float*)d_in[2];
  const float* wq    = (const float*)d_in[3];
  const float* wk    = (const float*)d_in[4];
  const float* wv    = (const float*)d_in[5];
  const float* wfc   = (const float*)d_in[6];
  const float* gamma = (const float*)d_in[7];
  const float* beta  = (const float*)d_in[8];
  float* out = (float*)d_out;
  char* ws = (char*)d_ws;
  short* Qh  = (short*)(ws);
  short* Kh  = (short*)(ws + 67108864);
  short* Vt  = (short*)(ws + 134217728);
  short* ctx = (short*)(ws + 201326592);
  float* Y   = (float*)(ws);  // fp32, aliases dead Qh (stream order)

  qkv_proj<<<dim3(64, 32, 3), 256, 0, stream>>>(q, k, v, wq, wk, wv, Qh, Kh, Vt);
  flash_attn<<<dim3(1024), 256, 0, stream>>>(Qh, Kh, Vt, ctx);
  fc_gemm<<<dim3(64, 4), 256, 0, stream>>>(ctx, wfc, q, Y);
  layernorm<<<2048, 256, 0, stream>>>(Y, gamma, beta, out);
}